// Round 9
// baseline (380.766 us; speedup 1.0000x reference)
//
#include <hip/hip_runtime.h>
#include <math.h>

namespace {
constexpr int N_ = 16, L_ = 256, S_ = 128, E_ = 128, A_ = 9, D_ = 768, H_ = 768, RO_ = 24;
constexpr int IDXW = 130;       // S+2
constexpr int W1R = 6 * D_;     // 4608
constexpr float INV_SQRT_D = 0.03608439182435161f; // 1/sqrt(768)
constexpr int PESZ = 2048 * 768;   // one Pe partial
constexpr int PASZ = 144 * 768;    // one Pa partial
// stage1 block ranges (longest work first); union LDS = 16.9 KB
constexpr int GB_T2T    = 0;       // 1024 (16 n x 64 s-pairs)
constexpr int GB_W1T    = 1024;    // 864  (72 k-tiles x 12 h-tiles)
constexpr int GB_GATHER = 1888;    // 192  (16 n x 12 d-tiles)
constexpr int GB_ENTMAP = 2080;    // 32   (16 n x 2 e-halves)
constexpr int GB_ARGU   = 2112;    // 16
constexpr int GB_TOTAL  = 2128;
} // namespace

using bshort8 = __attribute__((ext_vector_type(8))) short;
using f32x4v = __attribute__((ext_vector_type(4))) float;

__device__ __forceinline__ unsigned short f2bf(float f) {
    unsigned u = __builtin_bit_cast(unsigned, f);
    return (unsigned short)((u + 0x7fffu + ((u >> 16) & 1u)) >> 16);
}

// A&S 7.1.26 erf, |err| <= 1.5e-7 (<< bf16 noise floor)
__device__ __forceinline__ float erf_fast(float x) {
    const float ax = fabsf(x);
    const float t = 1.0f / fmaf(0.3275911f, ax, 1.0f);
    float p = fmaf(1.061405429f, t, -1.453152027f);
    p = fmaf(p, t, 1.421413741f);
    p = fmaf(p, t, -0.284496736f);
    p = fmaf(p, t, 0.254829592f);
    p = p * t;
    const float r = 1.0f - p * __expf(-ax * ax);
    return copysignf(r, x);
}

// shared 128x64-tile K=128 GEMM body: acc += A(128x128) @ B(128x64 from BT[col][k])
__device__ __forceinline__ void gemm_body128(const unsigned short* __restrict__ A,
                                             const unsigned short* __restrict__ BT,
                                             int lda, int ldb, int c0, int tid,
                                             short (*As)[40], short (*Bs)[40],
                                             f32x4v acc[2][4]) {
    const int wave = tid >> 6, lane = tid & 63;
    const int row16 = lane & 15, quad = lane >> 4;
    for (int k0 = 0; k0 < S_; k0 += 32) {
#pragma unroll
        for (int i = 0; i < 2; ++i) {
            const int idx = tid + 256 * i;
            const int r = idx >> 2, q = idx & 3;
            *reinterpret_cast<bshort8*>(&As[r][q * 8]) =
                *reinterpret_cast<const bshort8*>(A + (size_t)r * lda + k0 + q * 8);
        }
        {
            const int col = tid >> 2, q = tid & 3;
            *reinterpret_cast<bshort8*>(&Bs[col][q * 8]) =
                *reinterpret_cast<const bshort8*>(BT + (size_t)(c0 + col) * ldb + k0 + q * 8);
        }
        __syncthreads();
        bshort8 a[2], b[4];
#pragma unroll
        for (int mi = 0; mi < 2; ++mi)
            a[mi] = *reinterpret_cast<const bshort8*>(&As[wave * 32 + mi * 16 + row16][quad * 8]);
#pragma unroll
        for (int ni = 0; ni < 4; ++ni)
            b[ni] = *reinterpret_cast<const bshort8*>(&Bs[ni * 16 + row16][quad * 8]);
#pragma unroll
        for (int mi = 0; mi < 2; ++mi)
#pragma unroll
            for (int ni = 0; ni < 4; ++ni)
                acc[mi][ni] = __builtin_amdgcn_mfma_f32_16x16x32_bf16(a[mi], b[ni], acc[mi][ni], 0, 0, 0);
        __syncthreads();
    }
}

// ======== L1: all input-only transforms; union LDS 16.9 KB ========
__global__ __launch_bounds__(256) void stage1_k(const float* __restrict__ all_emb,
                                                const int* __restrict__ idxs,
                                                const float* __restrict__ ent_map,
                                                const float* __restrict__ W1,
                                                const float* __restrict__ argw,
                                                const float* __restrict__ attn,
                                                unsigned short* __restrict__ sentT,
                                                unsigned short* __restrict__ entmapT,
                                                short* __restrict__ W1t,
                                                unsigned short* __restrict__ t2tT,
                                                unsigned short* __restrict__ argEbf,
                                                unsigned short* __restrict__ u2ubf) {
    __shared__ __align__(16) unsigned char smem[16896];
    const int b = blockIdx.x, tid = threadIdx.x;

    if (b < GB_W1T) {
        // ---- t2t: two s-rows per block; output TRANSPOSED t2tT[n][t][s] ----
        const int idx = b - GB_T2T;
        const int n = idx >> 6;
        const int half = tid >> 7, t128 = tid & 127;
        const int s0 = (idx & 63) << 1;
        const int s = s0 | half;
        const int w = t128 >> 6, lane = tid & 63;
        float* sum2 = (float*)smem;                       // [2][3][2][256] = 12288B
        float* part = (float*)(smem + 12288);             // 12 floats
        unsigned short* tileT = (unsigned short*)(smem + 12544); // [128][2] = 512B
        const int is = idxs[n * IDXW + s], it = idxs[n * IDXW + t128];
#pragma unroll
        for (int l = 0; l < 3; ++l) {
            const float* base = attn + ((size_t)((l * N_ + n) * 12 + w * 6)) * (L_ * L_)
                              + (size_t)is * L_ + lane * 4;
            float4 acc = {0.f, 0.f, 0.f, 0.f};
#pragma unroll
            for (int h = 0; h < 6; ++h) {
                const float4 v = *reinterpret_cast<const float4*>(base + (size_t)h * (L_ * L_));
                acc.x += v.x; acc.y += v.y; acc.z += v.z; acc.w += v.w;
            }
            *reinterpret_cast<float4*>(&sum2[(((half * 3 + l) * 2 + w) << 8) + lane * 4]) = acc;
        }
        __syncthreads();
        float m[3];
#pragma unroll
        for (int l = 0; l < 3; ++l) {
            m[l] = (sum2[(((half * 3 + l) * 2 + 0) << 8) + it] +
                    sum2[(((half * 3 + l) * 2 + 1) << 8) + it]) * (1.0f / 12.0f);
            float r = m[l];
#pragma unroll
            for (int off = 32; off; off >>= 1) r += __shfl_xor(r, off, 64);
            if (lane == 0) part[(half * 3 + l) * 2 + w] = r;
        }
        __syncthreads();
        float o = 0.f;
#pragma unroll
        for (int l = 0; l < 3; ++l)
            o += m[l] / (part[(half * 3 + l) * 2 + 0] + part[(half * 3 + l) * 2 + 1] + 1e-9f);
        tileT[t128 * 2 + half] = f2bf(o * (1.0f / 3.0f));
        __syncthreads();
        if (tid < 128) {
            const unsigned int v = ((const unsigned int*)tileT)[tid];
            *reinterpret_cast<unsigned int*>(t2tT + ((size_t)(n * S_) + tid) * S_ + s0) = v;
        }
    } else if (b < GB_GATHER) {
        // ---- W1t[h][k] = bf16(W1[k][h]) ----
        const int b2 = b - GB_W1T;
        const int k0 = (b2 % 72) * 64, h0 = (b2 / 72) * 64;
        auto tile = (float (*)[65])smem;             // [64][65] = 16640B
        const int tx = tid & 63, ty = tid >> 6;
#pragma unroll
        for (int i = 0; i < 16; ++i) {
            const int r = ty + i * 4;
            tile[r][tx] = W1[(size_t)(k0 + r) * H_ + h0 + tx];
        }
        __syncthreads();
#pragma unroll
        for (int i = 0; i < 16; ++i) {
            const int r = ty + i * 4;
            W1t[(size_t)(h0 + r) * W1R + k0 + tx] = (short)f2bf(tile[tx][r]);
        }
    } else if (b < GB_ENTMAP) {
        // ---- gatherT: sentT[n][d][s] = bf16(all_emb[n][idx[s]][d]) ----
        const int b2 = b - GB_GATHER;
        const int n = b2 / 12, d0 = (b2 % 12) * 64;
        auto tile = (unsigned short (*)[132])smem;   // [64][132] = 16896B
#pragma unroll
        for (int it = 0; it < 8; ++it) {
            const int lin = tid + 256 * it;
            const int s = lin >> 4, dq = (lin & 15) * 4;
            const int row = idxs[n * IDXW + s];
            const float4 v = *reinterpret_cast<const float4*>(all_emb + ((size_t)(n * L_ + row)) * D_ + d0 + dq);
            tile[dq + 0][s] = f2bf(v.x); tile[dq + 1][s] = f2bf(v.y);
            tile[dq + 2][s] = f2bf(v.z); tile[dq + 3][s] = f2bf(v.w);
        }
        __syncthreads();
#pragma unroll
        for (int it = 0; it < 8; ++it) {
            const int lin = tid + 256 * it;
            const int d = lin >> 5, s4 = (lin & 31) * 4;
            ushort4 v = {tile[d][s4], tile[d][s4 + 1], tile[d][s4 + 2], tile[d][s4 + 3]};
            *reinterpret_cast<ushort4*>(sentT + ((size_t)(n * D_) + d0 + d) * S_ + s4) = v;
        }
    } else if (b < GB_ARGU) {
        // ---- entmapT[n][e0+e][s] = bf16(ent_map[n][s][e0+e]), 64-e chunks ----
        const int idx = b - GB_ENTMAP;
        const int n = idx >> 1, e0 = (idx & 1) * 64;
        auto tile = (unsigned short (*)[132])smem;   // [64][132]
#pragma unroll
        for (int it = 0; it < 8; ++it) {
            const int lin = tid + 256 * it;          // 128 s x 16 e-quads
            const int s = lin >> 4, eq = (lin & 15) * 4;
            const float4 v = *reinterpret_cast<const float4*>(ent_map + ((size_t)(n * S_ + s)) * E_ + e0 + eq);
            tile[eq + 0][s] = f2bf(v.x); tile[eq + 1][s] = f2bf(v.y);
            tile[eq + 2][s] = f2bf(v.z); tile[eq + 3][s] = f2bf(v.w);
        }
        __syncthreads();
#pragma unroll
        for (int it = 0; it < 8; ++it) {
            const int lin = tid + 256 * it;          // 64 e x 32 s-quads
            const int e = lin >> 5, s4 = (lin & 31) * 4;
            ushort4 v = {tile[e][s4], tile[e][s4 + 1], tile[e][s4 + 2], tile[e][s4 + 3]};
            *reinterpret_cast<ushort4*>(entmapT + ((size_t)(n * E_) + e0 + e) * S_ + s4) = v;
        }
    } else {
        // ---- arg_u2u: arg_emb (bf16) + a2a softmax + u2u ----
        const int n = b - GB_ARGU;
        auto wsm = (float (*)[A_])smem;
        auto part45 = (float (*)[4])(smem + 512);
        auto Psm = (float (*)[A_])(smem + 1536);
        if (tid < A_ * A_) wsm[tid / A_][tid % A_] = argw[n * A_ * A_ + tid];
        __syncthreads();
        const int p0 = idxs[n * IDXW + S_] + 1;
        float pp[45] = {};
        float vals[3][A_];
#pragma unroll
        for (int c = 0; c < 3; ++c) {
            const int d = tid + 256 * c;
            float raw[A_];
#pragma unroll
            for (int k = 0; k < A_; ++k) raw[k] = all_emb[((size_t)(n * L_ + p0 + k)) * D_ + d];
#pragma unroll
            for (int a = 0; a < A_; ++a) {
                float acc = 0.f;
#pragma unroll
                for (int k = 0; k < A_; ++k) acc = fmaf(raw[k], wsm[k][a], acc);
                vals[c][a] = acc;
                argEbf[((size_t)(n * A_ + a)) * D_ + d] = f2bf(acc);
            }
            int p = 0;
#pragma unroll
            for (int a = 0; a < A_; ++a)
#pragma unroll
                for (int bb = a; bb < A_; ++bb) pp[p++] += vals[c][a] * vals[c][bb];
        }
        const int lane = tid & 63, wv = tid >> 6;
#pragma unroll
        for (int p = 0; p < 45; ++p) {
            float v = pp[p];
            for (int off = 32; off; off >>= 1) v += __shfl_down(v, off, 64);
            if (lane == 0) part45[p][wv] = v;
        }
        __syncthreads();
        if (tid < 45) part45[tid][0] = part45[tid][0] + part45[tid][1] + part45[tid][2] + part45[tid][3];
        __syncthreads();
        if (tid < A_) {
            const int a = tid;
            float v[A_], mx = -1e30f;
#pragma unroll
            for (int bb = 0; bb < A_; ++bb) {
                const int lo = a < bb ? a : bb, hi = a < bb ? bb : a;
                v[bb] = part45[lo * (19 - lo) / 2 + hi - lo][0];
                mx = fmaxf(mx, v[bb]);
            }
            float sm = 0.f;
#pragma unroll
            for (int bb = 0; bb < A_; ++bb) { v[bb] = expf(v[bb] - mx); sm += v[bb]; }
            const float inv = 1.0f / sm;
#pragma unroll
            for (int bb = 0; bb < A_; ++bb) Psm[a][bb] = v[bb] * inv;
        }
        __syncthreads();
#pragma unroll
        for (int c = 0; c < 3; ++c) {
            const int d = tid + 256 * c;
#pragma unroll
            for (int a = 0; a < A_; ++a) {
                float acc = 0.f;
#pragma unroll
                for (int bb = 0; bb < A_; ++bb) acc = fmaf(Psm[a][bb], vals[c][bb], acc);
                u2ubf[((size_t)(n * A_ + a)) * D_ + d] = f2bf(acc);
            }
        }
    }
}

// ======== L2: ent (192) + M1 = entmapT@t2t (32) + argEW2 = argE@W1_2 (16, K-outer interleave) ========
__global__ __launch_bounds__(256) void gemm_pair_k(const unsigned short* __restrict__ entmapT,
                                                   const unsigned short* __restrict__ sentT,
                                                   const unsigned short* __restrict__ t2tT,
                                                   const unsigned short* __restrict__ argEbf,
                                                   const short* __restrict__ W1t,
                                                   float* __restrict__ entf,
                                                   unsigned short* __restrict__ entbf,
                                                   unsigned short* __restrict__ M1bf,
                                                   float* __restrict__ argEW2) {
    __shared__ __align__(16) short As[128][40];
    __shared__ __align__(16) short Bs[64][40];
    const int bx = blockIdx.x, tid = threadIdx.x;
    const int wave = tid >> 6, lane = tid & 63;
    const int row16 = lane & 15, quad = lane >> 4;
    if (bx < 192) {
        const int n = bx / 12, c0 = (bx % 12) * 64;
        f32x4v acc[2][4] = {};
        gemm_body128(entmapT + (size_t)n * S_ * S_, sentT + (size_t)n * D_ * S_,
                     S_, S_, c0, tid, As, Bs, acc);
#pragma unroll
        for (int mi = 0; mi < 2; ++mi)
#pragma unroll
            for (int ni = 0; ni < 4; ++ni) {
                const int rbase = wave * 32 + mi * 16 + quad * 4;
                const int col = c0 + ni * 16 + row16;
#pragma unroll
                for (int t = 0; t < 4; ++t) {
                    const size_t o = ((size_t)(n * S_) + rbase + t) * D_ + col;
                    entf[o] = acc[mi][ni][t];
                    entbf[o] = f2bf(acc[mi][ni][t]);
                }
            }
    } else if (bx < 224) {
        const int idx = bx - 192;                 // 0..31
        const int n = idx >> 1, c0 = (idx & 1) * 64;
        f32x4v acc[2][4] = {};
        gemm_body128(entmapT + (size_t)n * S_ * S_, t2tT + (size_t)n * S_ * S_,
                     S_, S_, c0, tid, As, Bs, acc);
#pragma unroll
        for (int mi = 0; mi < 2; ++mi)
#pragma unroll
            for (int ni = 0; ni < 4; ++ni) {
                const int rbase = wave * 32 + mi * 16 + quad * 4;
                const int col = c0 + ni * 16 + row16;
#pragma unroll
                for (int t = 0; t < 4; ++t)
                    M1bf[((size_t)(n * S_) + rbase + t) * S_ + col] = f2bf(acc[mi][ni][t]);
            }
    } else {
        // argEW2[n][a][h] = (argE @ W1_seg2)[a][h] (fp32), a<9.
        // K-OUTER / col-INNER: 13 independent loads per k-step feed 12 MFMAs, amortizing
        // load latency 12x (R8's col-outer form was a serial 12x24-step chain -> L2 straggler).
        // A rows 9..15 read overrun pad (u2ubf, finite values); output rows a>=9 masked.
        const int n = bx - 224;
        const unsigned short* Ar = argEbf + (size_t)n * A_ * D_;
        const unsigned short* BT = (const unsigned short*)W1t + (size_t)2 * D_;
        float* outp = argEW2 + (size_t)n * A_ * H_;
        f32x4v acc[12];
#pragma unroll
        for (int i = 0; i < 12; ++i) acc[i] = (f32x4v){0.f, 0.f, 0.f, 0.f};
        for (int k0 = 0; k0 < D_; k0 += 32) {
            const bshort8 a8 = *reinterpret_cast<const bshort8*>(Ar + (size_t)row16 * D_ + k0 + quad * 8);
#pragma unroll
            for (int i = 0; i < 12; ++i) {
                const int col0 = (wave * 12 + i) * 16;
                const bshort8 b8 = *reinterpret_cast<const bshort8*>(BT + (size_t)(col0 + row16) * W1R + k0 + quad * 8);
                acc[i] = __builtin_amdgcn_mfma_f32_16x16x32_bf16(a8, b8, acc[i], 0, 0, 0);
            }
        }
#pragma unroll
        for (int i = 0; i < 12; ++i) {
            const int col0 = (wave * 12 + i) * 16;
#pragma unroll
            for (int t = 0; t < 4; ++t) {
                const int a = quad * 4 + t;
                if (a < A_) outp[(size_t)a * H_ + col0 + row16] = acc[i][t];
            }
        }
    }
}

// ======== L3: Ah2h = M1@sent (192) + w via MFMA (16) ========
__global__ __launch_bounds__(256) void gemm2_k(const unsigned short* __restrict__ M1bf,
                                               const unsigned short* __restrict__ sentT,
                                               const unsigned short* __restrict__ entbf,
                                               const unsigned short* __restrict__ argEbf,
                                               unsigned short* __restrict__ Ah2hbf,
                                               float* __restrict__ wbuf) {
    const int bx = blockIdx.x, tid = threadIdx.x;
    const int wave = tid >> 6, lane = tid & 63;
    const int row16 = lane & 15, quad = lane >> 4;
    if (bx < 192) {
        __shared__ __align__(16) short As[128][40];
        __shared__ __align__(16) short Bs[64][40];
        const int n = bx / 12, c0 = (bx % 12) * 64;
        f32x4v acc[2][4] = {};
        gemm_body128(M1bf + (size_t)n * S_ * S_, sentT + (size_t)n * D_ * S_,
                     S_, S_, c0, tid, As, Bs, acc);
#pragma unroll
        for (int mi = 0; mi < 2; ++mi)
#pragma unroll
            for (int ni = 0; ni < 4; ++ni) {
                const int rbase = wave * 32 + mi * 16 + quad * 4;
                const int col = c0 + ni * 16 + row16;
#pragma unroll
                for (int t = 0; t < 4; ++t)
                    Ah2hbf[((size_t)(n * S_) + rbase + t) * D_ + col] = f2bf(acc[mi][ni][t]);
            }
    } else {
        // t2a via MFMA: C[128][16] = entbf[n](128x768) @ argEbf[n](9x768 padded)^T
        const int n = bx - 192;
        const unsigned short* Aent = entbf + (size_t)n * E_ * D_;
        const unsigned short* Barg = argEbf + (size_t)n * A_ * D_;
        f32x4v acc[2] = {};
        for (int k0 = 0; k0 < D_; k0 += 32) {
            bshort8 a[2], bb;
#pragma unroll
            for (int mi = 0; mi < 2; ++mi)
                a[mi] = *reinterpret_cast<const bshort8*>(Aent + (size_t)(wave * 32 + mi * 16 + row16) * D_ + k0 + quad * 8);
            bb = *reinterpret_cast<const bshort8*>(Barg + (size_t)row16 * D_ + k0 + quad * 8);
#pragma unroll
            for (int mi = 0; mi < 2; ++mi)
                acc[mi] = __builtin_amdgcn_mfma_f32_16x16x32_bf16(a[mi], bb, acc[mi], 0, 0, 0);
        }
        if (row16 < A_) {
#pragma unroll
            for (int mi = 0; mi < 2; ++mi)
#pragma unroll
                for (int t = 0; t < 4; ++t) {
                    const int e = wave * 32 + mi * 16 + quad * 4 + t;
                    const float w = (acc[mi][t] * INV_SQRT_D - 5.0f) * 0.5f;
                    wbuf[((size_t)(n * E_ + e)) * A_ + row16] = w;
                }
        }
    }
}

// ======== L4: argT[n,a,:] = sum_e w[n,e,a]*ent[n,e,:] (144 blocks) ========
__global__ __launch_bounds__(256) void argT_k(const float* __restrict__ wbuf,
                                              const float* __restrict__ entf,
                                              unsigned short* __restrict__ argTbf) {
    const int n = blockIdx.x / A_, a = blockIdx.x % A_;
    const int tid = threadIdx.x;
    __shared__ float wl[E_];
    if (tid < E_) wl[tid] = wbuf[(size_t)(n * E_ + tid) * A_ + a];
    __syncthreads();
    const float* eb = entf + (size_t)n * E_ * D_;
#pragma unroll
    for (int c = 0; c < 3; ++c) {
        const int d = tid + 256 * c;
        float acc = 0.f;
        for (int e = 0; e < E_; ++e) acc = fmaf(wl[e], eb[(size_t)e * D_ + d], acc);
        argTbf[((size_t)(n * A_ + a)) * D_ + d] = f2bf(acc);
    }
}

// ======== L5: MLP layer 1. Pe = {ent, Ah2h} segs (2 partials) + rank-9 w@argEW2 in seg0 epilogue;
//             Pa = {argE, argT, u2u} segs (3 partials). 38 x 12 blocks ========
__global__ __launch_bounds__(256) void mfma_mlp_k(const unsigned short* __restrict__ entbf,
                                                  const unsigned short* __restrict__ Ah2hbf,
                                                  const unsigned short* __restrict__ argEbf,
                                                  const unsigned short* __restrict__ argTbf,
                                                  const unsigned short* __restrict__ u2ubf,
                                                  const short* __restrict__ W1t,
                                                  const float* __restrict__ wbuf,
                                                  const float* __restrict__ argEW2,
                                                  float* __restrict__ Pe2, float* __restrict__ Pa3) {
    __shared__ __align__(16) short As[128][40];
    __shared__ __align__(16) short Bs[64][40];
    const int bx = blockIdx.x;          // 0..37
    const int c0 = blockIdx.y * 64;
    const bool isPe = bx < 32;
    int seg, blk, M, woff;
    const unsigned short* Aseg;
    float* C;
    if (isPe) {
        seg = bx >> 4; blk = bx & 15;
        Aseg = seg == 0 ? entbf : Ah2hbf;
        woff = seg == 0 ? 0 : 3 * D_;
        M = N_ * E_;
        C = Pe2 + (size_t)seg * PESZ;
    } else {
        const int q = bx - 32;
        seg = q >> 1; blk = q & 1;
        Aseg = seg == 0 ? argEbf : (seg == 1 ? argTbf : u2ubf);
        woff = seg == 0 ? 1 * D_ : (seg == 1 ? 4 * D_ : 5 * D_);
        M = N_ * A_;
        C = Pa3 + (size_t)seg * PASZ;
    }
    const int r0 = blk * 128;
    const int tid = threadIdx.x;
    const int wave = tid >> 6, lane = tid & 63;
    const int row16 = lane & 15, quad = lane >> 4;
    f32x4v acc[2][4] = {};
    for (int kk = 0; kk < D_; kk += 32) {
#pragma unroll
        for (int i = 0; i < 2; ++i) {
            const int idx = tid + 256 * i;
            const int r = idx >> 2, q = idx & 3;
            bshort8 av = {};
            if (r0 + r < M) av = *reinterpret_cast<const bshort8*>(Aseg + (size_t)(r0 + r) * D_ + kk + q * 8);
            *reinterpret_cast<bshort8*>(&As[r][q * 8]) = av;
        }
        {
            const int col = tid >> 2, q = tid & 3;
            *reinterpret_cast<bshort8*>(&Bs[col][q * 8]) =
                *reinterpret_cast<const bshort8*>(W1t + (size_t)(c0 + col) * W1R + woff + kk + q * 8);
        }
        __syncthreads();
        bshort8 a[2], b[4];
#pragma unroll
        for (int mi = 0; mi < 2; ++mi)
            a[mi] = *reinterpret_cast<const bshort8*>(&As[wave * 32 + mi * 16 + row16][quad * 8]);
#pragma unroll
        for (int ni = 0; ni < 4; ++ni)
            b[ni] = *reinterpret_cast<const bshort8*>(&Bs[ni * 16 + row16][quad * 8]);
#pragma unroll
        for (int mi = 0; mi < 2; ++mi)
#pragma unroll
            for (int ni = 0; ni < 4; ++ni)
                acc[mi][ni] = __builtin_amdgcn_mfma_f32_16x16x32_bf16(a[mi], b[ni], acc[mi][ni], 0, 0, 0);
        __syncthreads();
    }
    // seg0-Pe epilogue staging: wS (128x9) and aW2 (9x64) reuse As/Bs LDS (all waves past final sync)
    float* wS = (float*)As;
    float* aW2 = (float*)Bs;
    if (isPe && seg == 0) {
        const int n = blk;
        for (int i = tid; i < E_ * A_; i += 256) wS[i] = wbuf[(size_t)n * E_ * A_ + i];
        for (int i = tid; i < A_ * 64; i += 256)
            aW2[i] = argEW2[((size_t)(n * A_) + (i >> 6)) * H_ + c0 + (i & 63)];
        __syncthreads();
    }
#pragma unroll
    for (int mi = 0; mi < 2; ++mi) {
#pragma unroll
        for (int ni = 0; ni < 4; ++ni) {
            const int lrow = wave * 32 + mi * 16 + quad * 4;
            const int col = c0 + ni * 16 + row16;
#pragma unroll
            for (int t = 0; t < 4; ++t) {
                const int g = r0 + lrow + t;
                if (g < M) {
                    float v = acc[mi][ni][t];
                    if (isPe && seg == 0) {
                        const int e = lrow + t;
#pragma unroll
                        for (int a = 0; a < A_; ++a)
                            v = fmaf(wS[e * A_ + a], aW2[a * 64 + ni * 16 + row16], v);
                    }
                    C[(size_t)g * H_ + col] = v;
                }
            }
        }
    }
}

// ======== L6: gelu(Pe0+Pe1+ΣPa+b1)@W2 + b2, scatter ========
__global__ __launch_bounds__(256) void score_k(const float* __restrict__ Pe2, const float* __restrict__ Pa3,
                                               const float* __restrict__ b1, const float* __restrict__ W2,
                                               const float* __restrict__ b2, const int* __restrict__ arg_map,
                                               float* __restrict__ out) {
    const int n = blockIdx.x >> 7, e = blockIdx.x & 127;
    const int tid = threadIdx.x;
    __shared__ float paS[A_ * H_];
    __shared__ float part[A_][4];
    float* orow = out + ((size_t)(n * E_ + e)) * RO_;
    if (tid < RO_) orow[tid] = -1000000.0f;
    for (int i = tid; i < A_ * H_; i += 256) {
        const size_t o = (size_t)n * A_ * H_ + i;
        paS[i] = Pa3[o] + Pa3[PASZ + o] + Pa3[2 * PASZ + o];
    }
    __syncthreads();
    const size_t ro = ((size_t)(n * E_ + e)) * H_;
    float acc[A_] = {};
    for (int h = tid; h < H_; h += 256) {
        const float pe = Pe2[ro + h] + Pe2[PESZ + ro + h] + b1[h];
        const float w2 = W2[h];
#pragma unroll
        for (int a = 0; a < A_; ++a) {
            const float x = pe + paS[a * H_ + h];
            const float g = x * 0.5f * (1.0f + erf_fast(x * 0.70710678118654752f));
            acc[a] = fmaf(g, w2, acc[a]);
        }
    }
    const int lane = tid & 63, wv = tid >> 6;
#pragma unroll
    for (int a = 0; a < A_; ++a)
        for (int off = 32; off; off >>= 1) acc[a] += __shfl_down(acc[a], off, 64);
    if (lane == 0)
        for (int a = 0; a < A_; ++a) part[a][wv] = acc[a];
    __syncthreads();
    if (tid < A_) {
        const float s = part[tid][0] + part[tid][1] + part[tid][2] + part[tid][3] + b2[0];
        orow[arg_map[n * A_ + tid]] = s;
    }
}

extern "C" void kernel_launch(void* const* d_in, const int* in_sizes, int n_in,
                              void* d_out, int out_size, void* d_ws, size_t ws_size,
                              hipStream_t stream) {
    const float* all_emb = (const float*)d_in[0];
    const float* attn    = (const float*)d_in[1];
    const float* ent_map = (const float*)d_in[2];
    const float* argw    = (const float*)d_in[3];
    // d_in[4] is_triggers unused (reference dead code)
    const float* W1 = (const float*)d_in[5];
    const float* b1 = (const float*)d_in[6];
    const float* W2 = (const float*)d_in[7];
    const float* b2 = (const float*)d_in[8];
    const int* idxs    = (const int*)d_in[9];
    const int* arg_map = (const int*)d_in[10];
    float* out = (float*)d_out;

    float* ws = (float*)d_ws;
    // fp32 buffers (float offsets)
    float* entf   = ws + 0;             // N*E*D           = 1,572,864
    float* Pe2    = ws + 1572864;       // 2*N*E*H         = 3,145,728  -> 4,718,592
    float* wbuf   = ws + 4718592;       // N*E*A           =    18,432  -> 4,737,024
    float* Pa3    = ws + 4737024;       // 3*N*A*H         =   331,776  -> 5,068,800
    float* argEW2 = ws + 5068800;       // N*A*H           =   110,592  -> 5,179,392
    // bf16 buffers (offsets in float-slots; sizes in SHORTS; float-slots = shorts/2)
    short*          W1t     = (short*)(ws + 5179392);          // 3,538,944 sh = 1,769,472 fl -> 6,948,864
    unsigned short* sentT   = (unsigned short*)(ws + 6948864); // N*D*S = 1,572,864 sh = 786,432 fl -> 7,735,296
    unsigned short* entmapT = (unsigned short*)(ws + 7735296); // N*E*S =   262,144 sh = 131,072 fl -> 7,866,368
    unsigned short* t2tT    = (unsigned short*)(ws + 7866368); // N*S*S =   262,144 sh = 131,072 fl -> 7,997,440
    unsigned short* M1bf    = (unsigned short*)(ws + 7997440); // N*E*S =   262,144 sh = 131,072 fl -> 8,128,512
    unsigned short* argEbf  = (unsigned short*)(ws + 8128512); // N*A*D =   110,592 sh =  55,296 fl -> 8,183,808
    unsigned short* u2ubf   = (unsigned short*)(ws + 8183808); // N*A*D =   110,592 sh =  55,296 fl -> 8,239,104 (pads argEbf overrun)
    unsigned short* entbf   = (unsigned short*)(ws + 8239104); // N*E*D = 1,572,864 sh = 786,432 fl -> 9,025,536
    unsigned short* Ah2hbf  = (unsigned short*)(ws + 9025536); // N*E*D = 1,572,864 sh = 786,432 fl -> 9,811,968
    unsigned short* argTbf  = (unsigned short*)(ws + 9811968); // N*A*D =   110,592 sh =  55,296 fl -> 9,867,264
    // total ≈ 9.87M floats ≈ 39.5 MB

    // L1: all input-only transforms (2128 blocks)
    stage1_k<<<GB_TOTAL, 256, 0, stream>>>(all_emb, idxs, ent_map, W1, argw, attn,
                                           sentT, entmapT, W1t, t2tT, argEbf, u2ubf);

    // L2: ent (192) + M1 = entmapT@t2t (32) + argEW2 = argE@W1_2 (16, latency-fixed)
    gemm_pair_k<<<240, 256, 0, stream>>>(entmapT, sentT, t2tT, argEbf, W1t,
                                         entf, entbf, M1bf, argEW2);

    // L3: Ah2h = M1@sent (192) + w via MFMA (16)
    gemm2_k<<<208, 256, 0, stream>>>(M1bf, sentT, entbf, argEbf, Ah2hbf, wbuf);

    // L4: argT only (tokA eliminated by reassociation) — 144 blocks
    argT_k<<<N_ * A_, 256, 0, stream>>>(wbuf, entf, argTbf);

    // L5: MLP layer 1 — Pe {ent, Ah2h} + rank-9 tokA-term in epilogue; Pa {argE, argT, u2u}
    // W1 row blocks: [ent 0 | argE 768 | tokA 1536 | Ah2h 2304 | argT 3072 | u2u 3840]
    mfma_mlp_k<<<dim3(38, H_ / 64), 256, 0, stream>>>(entbf, Ah2hbf, argEbf, argTbf, u2ubf,
                                                      W1t, wbuf, argEW2, Pe2, Pa3);

    // L6: gelu + W2 + scatter
    score_k<<<N_ * E_, 256, 0, stream>>>(Pe2, Pa3, b1, W2, b2, arg_map, out);

    (void)in_sizes; (void)n_in; (void)out_size; (void)ws_size;
}

// Round 10
// 315.083 us; speedup vs baseline: 1.2085x; 1.2085x over previous
//
#include <hip/hip_runtime.h>
#include <math.h>

namespace {
constexpr int N_ = 16, L_ = 256, S_ = 128, E_ = 128, A_ = 9, D_ = 768, H_ = 768, RO_ = 24;
constexpr int IDXW = 130;       // S+2
constexpr int W1R = 6 * D_;     // 4608
constexpr float INV_SQRT_D = 0.03608439182435161f; // 1/sqrt(768)
constexpr int PESZ = 2048 * 768;   // one Pe partial
constexpr int PASZ = 144 * 768;    // one Pa partial
// stage1 block ranges (longest work first); union LDS = 16.9 KB
constexpr int GB_T2T    = 0;       // 1024 (16 n x 64 s-pairs)
constexpr int GB_W1T    = 1024;    // 864  (72 k-tiles x 12 h-tiles)
constexpr int GB_GATHER = 1888;    // 192  (16 n x 12 d-tiles)
constexpr int GB_ENTMAP = 2080;    // 32   (16 n x 2 e-halves)
constexpr int GB_ARGU   = 2112;    // 16
constexpr int GB_TOTAL  = 2128;
} // namespace

using bshort8 = __attribute__((ext_vector_type(8))) short;
using f32x4v = __attribute__((ext_vector_type(4))) float;

__device__ __forceinline__ unsigned short f2bf(float f) {
    unsigned u = __builtin_bit_cast(unsigned, f);
    return (unsigned short)((u + 0x7fffu + ((u >> 16) & 1u)) >> 16);
}

// A&S 7.1.26 erf, |err| <= 1.5e-7 (<< bf16 noise floor)
__device__ __forceinline__ float erf_fast(float x) {
    const float ax = fabsf(x);
    const float t = 1.0f / fmaf(0.3275911f, ax, 1.0f);
    float p = fmaf(1.061405429f, t, -1.453152027f);
    p = fmaf(p, t, 1.421413741f);
    p = fmaf(p, t, -0.284496736f);
    p = fmaf(p, t, 0.254829592f);
    p = p * t;
    const float r = 1.0f - p * __expf(-ax * ax);
    return copysignf(r, x);
}

// shared 128x64-tile K=128 GEMM body: acc += A(128x128) @ B(128x64 from BT[col][k])
__device__ __forceinline__ void gemm_body128(const unsigned short* __restrict__ A,
                                             const unsigned short* __restrict__ BT,
                                             int lda, int ldb, int c0, int tid,
                                             short (*As)[40], short (*Bs)[40],
                                             f32x4v acc[2][4]) {
    const int wave = tid >> 6, lane = tid & 63;
    const int row16 = lane & 15, quad = lane >> 4;
    for (int k0 = 0; k0 < S_; k0 += 32) {
#pragma unroll
        for (int i = 0; i < 2; ++i) {
            const int idx = tid + 256 * i;
            const int r = idx >> 2, q = idx & 3;
            *reinterpret_cast<bshort8*>(&As[r][q * 8]) =
                *reinterpret_cast<const bshort8*>(A + (size_t)r * lda + k0 + q * 8);
        }
        {
            const int col = tid >> 2, q = tid & 3;
            *reinterpret_cast<bshort8*>(&Bs[col][q * 8]) =
                *reinterpret_cast<const bshort8*>(BT + (size_t)(c0 + col) * ldb + k0 + q * 8);
        }
        __syncthreads();
        bshort8 a[2], b[4];
#pragma unroll
        for (int mi = 0; mi < 2; ++mi)
            a[mi] = *reinterpret_cast<const bshort8*>(&As[wave * 32 + mi * 16 + row16][quad * 8]);
#pragma unroll
        for (int ni = 0; ni < 4; ++ni)
            b[ni] = *reinterpret_cast<const bshort8*>(&Bs[ni * 16 + row16][quad * 8]);
#pragma unroll
        for (int mi = 0; mi < 2; ++mi)
#pragma unroll
            for (int ni = 0; ni < 4; ++ni)
                acc[mi][ni] = __builtin_amdgcn_mfma_f32_16x16x32_bf16(a[mi], b[ni], acc[mi][ni], 0, 0, 0);
        __syncthreads();
    }
}

// ======== stage 1 mega-kernel: all input-only transforms; union LDS 16.9 KB ========
__global__ __launch_bounds__(256) void stage1_k(const float* __restrict__ all_emb,
                                                const int* __restrict__ idxs,
                                                const float* __restrict__ ent_map,
                                                const float* __restrict__ W1,
                                                const float* __restrict__ argw,
                                                const float* __restrict__ attn,
                                                unsigned short* __restrict__ sentT,
                                                unsigned short* __restrict__ entmapT,
                                                short* __restrict__ W1t,
                                                unsigned short* __restrict__ t2tT,
                                                float* __restrict__ argE,
                                                unsigned short* __restrict__ argEbf,
                                                unsigned short* __restrict__ u2ubf) {
    __shared__ __align__(16) unsigned char smem[16896];
    const int b = blockIdx.x, tid = threadIdx.x;

    if (b < GB_W1T) {
        // ---- t2t: two s-rows per block; output TRANSPOSED t2tT[n][t][s] ----
        const int idx = b - GB_T2T;
        const int n = idx >> 6;
        const int half = tid >> 7, t128 = tid & 127;
        const int s0 = (idx & 63) << 1;
        const int s = s0 | half;
        const int w = t128 >> 6, lane = tid & 63;
        float* sum2 = (float*)smem;                       // [2][3][2][256] = 12288B
        float* part = (float*)(smem + 12288);             // 12 floats
        unsigned short* tileT = (unsigned short*)(smem + 12544); // [128][2] = 512B
        const int is = idxs[n * IDXW + s], it = idxs[n * IDXW + t128];
#pragma unroll
        for (int l = 0; l < 3; ++l) {
            const float* base = attn + ((size_t)((l * N_ + n) * 12 + w * 6)) * (L_ * L_)
                              + (size_t)is * L_ + lane * 4;
            float4 acc = {0.f, 0.f, 0.f, 0.f};
#pragma unroll
            for (int h = 0; h < 6; ++h) {
                const float4 v = *reinterpret_cast<const float4*>(base + (size_t)h * (L_ * L_));
                acc.x += v.x; acc.y += v.y; acc.z += v.z; acc.w += v.w;
            }
            *reinterpret_cast<float4*>(&sum2[(((half * 3 + l) * 2 + w) << 8) + lane * 4]) = acc;
        }
        __syncthreads();
        float m[3];
#pragma unroll
        for (int l = 0; l < 3; ++l) {
            m[l] = (sum2[(((half * 3 + l) * 2 + 0) << 8) + it] +
                    sum2[(((half * 3 + l) * 2 + 1) << 8) + it]) * (1.0f / 12.0f);
            float r = m[l];
#pragma unroll
            for (int off = 32; off; off >>= 1) r += __shfl_xor(r, off, 64);
            if (lane == 0) part[(half * 3 + l) * 2 + w] = r;
        }
        __syncthreads();
        float o = 0.f;
#pragma unroll
        for (int l = 0; l < 3; ++l)
            o += m[l] / (part[(half * 3 + l) * 2 + 0] + part[(half * 3 + l) * 2 + 1] + 1e-9f);
        tileT[t128 * 2 + half] = f2bf(o * (1.0f / 3.0f));
        __syncthreads();
        if (tid < 128) {
            const unsigned int v = ((const unsigned int*)tileT)[tid];
            *reinterpret_cast<unsigned int*>(t2tT + ((size_t)(n * S_) + tid) * S_ + s0) = v;
        }
    } else if (b < GB_GATHER) {
        // ---- W1t[h][k] = bf16(W1[k][h]) ----
        const int b2 = b - GB_W1T;
        const int k0 = (b2 % 72) * 64, h0 = (b2 / 72) * 64;
        auto tile = (float (*)[65])smem;             // [64][65] = 16640B
        const int tx = tid & 63, ty = tid >> 6;
#pragma unroll
        for (int i = 0; i < 16; ++i) {
            const int r = ty + i * 4;
            tile[r][tx] = W1[(size_t)(k0 + r) * H_ + h0 + tx];
        }
        __syncthreads();
#pragma unroll
        for (int i = 0; i < 16; ++i) {
            const int r = ty + i * 4;
            W1t[(size_t)(h0 + r) * W1R + k0 + tx] = (short)f2bf(tile[tx][r]);
        }
    } else if (b < GB_ENTMAP) {
        // ---- gatherT: sentT[n][d][s] = bf16(all_emb[n][idx[s]][d]) ----
        const int b2 = b - GB_GATHER;
        const int n = b2 / 12, d0 = (b2 % 12) * 64;
        auto tile = (unsigned short (*)[132])smem;   // [64][132] = 16896B
#pragma unroll
        for (int it = 0; it < 8; ++it) {
            const int lin = tid + 256 * it;
            const int s = lin >> 4, dq = (lin & 15) * 4;
            const int row = idxs[n * IDXW + s];
            const float4 v = *reinterpret_cast<const float4*>(all_emb + ((size_t)(n * L_ + row)) * D_ + d0 + dq);
            tile[dq + 0][s] = f2bf(v.x); tile[dq + 1][s] = f2bf(v.y);
            tile[dq + 2][s] = f2bf(v.z); tile[dq + 3][s] = f2bf(v.w);
        }
        __syncthreads();
#pragma unroll
        for (int it = 0; it < 8; ++it) {
            const int lin = tid + 256 * it;
            const int d = lin >> 5, s4 = (lin & 31) * 4;
            ushort4 v = {tile[d][s4], tile[d][s4 + 1], tile[d][s4 + 2], tile[d][s4 + 3]};
            *reinterpret_cast<ushort4*>(sentT + ((size_t)(n * D_) + d0 + d) * S_ + s4) = v;
        }
    } else if (b < GB_ARGU) {
        // ---- entmapT[n][e0+e][s] = bf16(ent_map[n][s][e0+e]), 64-e chunks ----
        const int idx = b - GB_ENTMAP;
        const int n = idx >> 1, e0 = (idx & 1) * 64;
        auto tile = (unsigned short (*)[132])smem;   // [64][132]
#pragma unroll
        for (int it = 0; it < 8; ++it) {
            const int lin = tid + 256 * it;          // 128 s x 16 e-quads
            const int s = lin >> 4, eq = (lin & 15) * 4;
            const float4 v = *reinterpret_cast<const float4*>(ent_map + ((size_t)(n * S_ + s)) * E_ + e0 + eq);
            tile[eq + 0][s] = f2bf(v.x); tile[eq + 1][s] = f2bf(v.y);
            tile[eq + 2][s] = f2bf(v.z); tile[eq + 3][s] = f2bf(v.w);
        }
        __syncthreads();
#pragma unroll
        for (int it = 0; it < 8; ++it) {
            const int lin = tid + 256 * it;          // 64 e x 32 s-quads
            const int e = lin >> 5, s4 = (lin & 31) * 4;
            ushort4 v = {tile[e][s4], tile[e][s4 + 1], tile[e][s4 + 2], tile[e][s4 + 3]};
            *reinterpret_cast<ushort4*>(entmapT + ((size_t)(n * E_) + e0 + e) * S_ + s4) = v;
        }
    } else {
        // ---- arg_u2u: arg_emb + a2a softmax + u2u ----
        const int n = b - GB_ARGU;
        auto wsm = (float (*)[A_])smem;
        auto part45 = (float (*)[4])(smem + 512);
        auto Psm = (float (*)[A_])(smem + 1536);
        if (tid < A_ * A_) wsm[tid / A_][tid % A_] = argw[n * A_ * A_ + tid];
        __syncthreads();
        const int p0 = idxs[n * IDXW + S_] + 1;
        float pp[45] = {};
        float vals[3][A_];
#pragma unroll
        for (int c = 0; c < 3; ++c) {
            const int d = tid + 256 * c;
            float raw[A_];
#pragma unroll
            for (int k = 0; k < A_; ++k) raw[k] = all_emb[((size_t)(n * L_ + p0 + k)) * D_ + d];
#pragma unroll
            for (int a = 0; a < A_; ++a) {
                float acc = 0.f;
#pragma unroll
                for (int k = 0; k < A_; ++k) acc = fmaf(raw[k], wsm[k][a], acc);
                vals[c][a] = acc;
                argE[((size_t)(n * A_ + a)) * D_ + d] = acc;
                argEbf[((size_t)(n * A_ + a)) * D_ + d] = f2bf(acc);
            }
            int p = 0;
#pragma unroll
            for (int a = 0; a < A_; ++a)
#pragma unroll
                for (int bb = a; bb < A_; ++bb) pp[p++] += vals[c][a] * vals[c][bb];
        }
        const int lane = tid & 63, wv = tid >> 6;
#pragma unroll
        for (int p = 0; p < 45; ++p) {
            float v = pp[p];
            for (int off = 32; off; off >>= 1) v += __shfl_down(v, off, 64);
            if (lane == 0) part45[p][wv] = v;
        }
        __syncthreads();
        if (tid < 45) part45[tid][0] = part45[tid][0] + part45[tid][1] + part45[tid][2] + part45[tid][3];
        __syncthreads();
        if (tid < A_) {
            const int a = tid;
            float v[A_], mx = -1e30f;
#pragma unroll
            for (int bb = 0; bb < A_; ++bb) {
                const int lo = a < bb ? a : bb, hi = a < bb ? bb : a;
                v[bb] = part45[lo * (19 - lo) / 2 + hi - lo][0];
                mx = fmaxf(mx, v[bb]);
            }
            float sm = 0.f;
#pragma unroll
            for (int bb = 0; bb < A_; ++bb) { v[bb] = expf(v[bb] - mx); sm += v[bb]; }
            const float inv = 1.0f / sm;
#pragma unroll
            for (int bb = 0; bb < A_; ++bb) Psm[a][bb] = v[bb] * inv;
        }
        __syncthreads();
#pragma unroll
        for (int c = 0; c < 3; ++c) {
            const int d = tid + 256 * c;
#pragma unroll
            for (int a = 0; a < A_; ++a) {
                float acc = 0.f;
#pragma unroll
                for (int bb = 0; bb < A_; ++bb) acc = fmaf(Psm[a][bb], vals[c][bb], acc);
                u2ubf[((size_t)(n * A_ + a)) * D_ + d] = f2bf(acc);
            }
        }
    }
}

// ======== stage 2: ent = entmapT@sent (192) + M1 = entmapT@t2t (32) ========
__global__ __launch_bounds__(256) void gemm_pair_k(const unsigned short* __restrict__ entmapT,
                                                   const unsigned short* __restrict__ sentT,
                                                   const unsigned short* __restrict__ t2tT,
                                                   float* __restrict__ entf,
                                                   unsigned short* __restrict__ entbf,
                                                   unsigned short* __restrict__ M1bf) {
    __shared__ __align__(16) short As[128][40];
    __shared__ __align__(16) short Bs[64][40];
    const int bx = blockIdx.x, tid = threadIdx.x;
    const int wave = tid >> 6, lane = tid & 63;
    const int row16 = lane & 15, quad = lane >> 4;
    f32x4v acc[2][4] = {};
    if (bx < 192) {
        const int n = bx / 12, c0 = (bx % 12) * 64;
        gemm_body128(entmapT + (size_t)n * S_ * S_, sentT + (size_t)n * D_ * S_,
                     S_, S_, c0, tid, As, Bs, acc);
#pragma unroll
        for (int mi = 0; mi < 2; ++mi)
#pragma unroll
            for (int ni = 0; ni < 4; ++ni) {
                const int rbase = wave * 32 + mi * 16 + quad * 4;
                const int col = c0 + ni * 16 + row16;
#pragma unroll
                for (int t = 0; t < 4; ++t) {
                    const size_t o = ((size_t)(n * S_) + rbase + t) * D_ + col;
                    entf[o] = acc[mi][ni][t];
                    entbf[o] = f2bf(acc[mi][ni][t]);
                }
            }
    } else {
        const int idx = bx - 192;                 // 0..31
        const int n = idx >> 1, c0 = (idx & 1) * 64;
        gemm_body128(entmapT + (size_t)n * S_ * S_, t2tT + (size_t)n * S_ * S_,
                     S_, S_, c0, tid, As, Bs, acc);
#pragma unroll
        for (int mi = 0; mi < 2; ++mi)
#pragma unroll
            for (int ni = 0; ni < 4; ++ni) {
                const int rbase = wave * 32 + mi * 16 + quad * 4;
                const int col = c0 + ni * 16 + row16;
#pragma unroll
                for (int t = 0; t < 4; ++t)
                    M1bf[((size_t)(n * S_) + rbase + t) * S_ + col] = f2bf(acc[mi][ni][t]);
            }
    }
}

// ======== stage 3: Ah2h = M1@sent (192) + w via MFMA (16) ========
__global__ __launch_bounds__(256) void gemm2_k(const unsigned short* __restrict__ M1bf,
                                               const unsigned short* __restrict__ sentT,
                                               const unsigned short* __restrict__ entbf,
                                               const unsigned short* __restrict__ argEbf,
                                               unsigned short* __restrict__ Ah2hbf,
                                               float* __restrict__ wbuf) {
    const int bx = blockIdx.x, tid = threadIdx.x;
    const int wave = tid >> 6, lane = tid & 63;
    const int row16 = lane & 15, quad = lane >> 4;
    if (bx < 192) {
        __shared__ __align__(16) short As[128][40];
        __shared__ __align__(16) short Bs[64][40];
        const int n = bx / 12, c0 = (bx % 12) * 64;
        f32x4v acc[2][4] = {};
        gemm_body128(M1bf + (size_t)n * S_ * S_, sentT + (size_t)n * D_ * S_,
                     S_, S_, c0, tid, As, Bs, acc);
#pragma unroll
        for (int mi = 0; mi < 2; ++mi)
#pragma unroll
            for (int ni = 0; ni < 4; ++ni) {
                const int rbase = wave * 32 + mi * 16 + quad * 4;
                const int col = c0 + ni * 16 + row16;
#pragma unroll
                for (int t = 0; t < 4; ++t)
                    Ah2hbf[((size_t)(n * S_) + rbase + t) * D_ + col] = f2bf(acc[mi][ni][t]);
            }
    } else {
        // t2a via MFMA: C[128][16] = entbf[n](128x768) @ argEbf[n](9x768 padded)^T
        // then w = (C/sqrt(D) - 5)/2 -> wbuf[n][e][a]
        const int n = bx - 192;
        const unsigned short* Aent = entbf + (size_t)n * E_ * D_;
        const unsigned short* Barg = argEbf + (size_t)n * A_ * D_;
        f32x4v acc[2] = {};
        for (int k0 = 0; k0 < D_; k0 += 32) {
            bshort8 a[2], bb;
#pragma unroll
            for (int mi = 0; mi < 2; ++mi)
                a[mi] = *reinterpret_cast<const bshort8*>(Aent + (size_t)(wave * 32 + mi * 16 + row16) * D_ + k0 + quad * 8);
            // rows 9..15 read past argE[n] into adjacent workspace (allocated); cols 9..15 discarded
            bb = *reinterpret_cast<const bshort8*>(Barg + (size_t)row16 * D_ + k0 + quad * 8);
#pragma unroll
            for (int mi = 0; mi < 2; ++mi)
                acc[mi] = __builtin_amdgcn_mfma_f32_16x16x32_bf16(a[mi], bb, acc[mi], 0, 0, 0);
        }
        if (row16 < A_) {
#pragma unroll
            for (int mi = 0; mi < 2; ++mi)
#pragma unroll
                for (int t = 0; t < 4; ++t) {
                    const int e = wave * 32 + mi * 16 + quad * 4 + t;
                    const float w = (acc[mi][t] * INV_SQRT_D - 5.0f) * 0.5f;
                    wbuf[((size_t)(n * E_ + e)) * A_ + row16] = w;
                }
        }
    }
}

// ======== stage 4: tokA (2048) + argT (144), both read wbuf ========
__global__ __launch_bounds__(256) void post_k(const float* __restrict__ wbuf,
                                              const float* __restrict__ argE,
                                              const float* __restrict__ entf,
                                              unsigned short* __restrict__ tokAbf,
                                              unsigned short* __restrict__ argTbf) {
    const int b = blockIdx.x, tid = threadIdx.x;
    if (b < N_ * E_) {
        // tokA[n,e,:] = sum_a w[n,e,a]*argE[n,a,:]
        const int n = b >> 7, e = b & 127;
        __shared__ float wl[A_];
        if (tid < A_) wl[tid] = wbuf[(size_t)(n * E_ + e) * A_ + tid];
        __syncthreads();
        const float* ar = argE + (size_t)n * A_ * D_;
#pragma unroll
        for (int c = 0; c < 3; ++c) {
            const int d = tid + 256 * c;
            float s = 0.f;
#pragma unroll
            for (int a = 0; a < A_; ++a) s = fmaf(wl[a], ar[(size_t)a * D_ + d], s);
            tokAbf[((size_t)(n * E_ + e)) * D_ + d] = f2bf(s);
        }
    } else {
        // argT[n,a,:] = sum_e w[n,e,a]*ent[n,e,:]
        // e-outer / 3-column-inner: 3 independent FMA chains + batched loads per step
        // (was 3 back-to-back 128-long serial load->FMA chains; same per-acc summation order)
        const int idx = b - N_ * E_;
        const int n = idx / A_, a = idx % A_;
        __shared__ float wl[E_];
        if (tid < E_) wl[tid] = wbuf[(size_t)(n * E_ + tid) * A_ + a];
        __syncthreads();
        const float* eb = entf + (size_t)n * E_ * D_ + tid;
        float acc0 = 0.f, acc1 = 0.f, acc2 = 0.f;
        for (int e = 0; e < E_; ++e) {
            const float we = wl[e];
            const float* er = eb + (size_t)e * D_;
            acc0 = fmaf(we, er[0],   acc0);
            acc1 = fmaf(we, er[256], acc1);
            acc2 = fmaf(we, er[512], acc2);
        }
        unsigned short* ob = argTbf + ((size_t)(n * A_ + a)) * D_ + tid;
        ob[0]   = f2bf(acc0);
        ob[256] = f2bf(acc1);
        ob[512] = f2bf(acc2);
    }
}

// ======== stage 5: MLP layer 1, K-split into 3 disjoint partial buffers (no atomics) ========
__global__ __launch_bounds__(256) void mfma_mlp_k(const unsigned short* __restrict__ e0,
                                                  const unsigned short* __restrict__ e1,
                                                  const unsigned short* __restrict__ e2,
                                                  const unsigned short* __restrict__ a0,
                                                  const unsigned short* __restrict__ a1,
                                                  const unsigned short* __restrict__ a2,
                                                  const short* __restrict__ W1t,
                                                  float* __restrict__ Pe3, float* __restrict__ Pa3) {
    __shared__ __align__(16) short As[128][40];
    __shared__ __align__(16) short Bs[64][40];
    const int bx = blockIdx.x;          // 0..53
    const int seg = bx % 3;
    const int blk = bx / 3;             // 0..17 (16 Pe row-blocks + 2 Pa row-blocks)
    const bool isPa = blk >= 16;
    const unsigned short* Aseg;
    int woff;
    if (isPa) {
        Aseg = seg == 0 ? a0 : (seg == 1 ? a1 : a2);
        woff = seg == 0 ? 1 * D_ : (seg == 1 ? 4 * D_ : 5 * D_);
    } else {
        Aseg = seg == 0 ? e0 : (seg == 1 ? e1 : e2);
        woff = seg == 0 ? 0 : (seg == 1 ? 2 * D_ : 3 * D_);
    }
    const int M = isPa ? N_ * A_ : N_ * E_;
    const int r0 = (isPa ? blk - 16 : blk) * 128;
    float* C = isPa ? (Pa3 + (size_t)seg * PASZ) : (Pe3 + (size_t)seg * PESZ);
    const int c0 = blockIdx.y * 64;
    const int tid = threadIdx.x;
    const int wave = tid >> 6, lane = tid & 63;
    const int row16 = lane & 15, quad = lane >> 4;
    f32x4v acc[2][4] = {};
    for (int kk = 0; kk < D_; kk += 32) {
#pragma unroll
        for (int i = 0; i < 2; ++i) {
            const int idx = tid + 256 * i;
            const int r = idx >> 2, q = idx & 3;
            bshort8 av = {};
            if (r0 + r < M) av = *reinterpret_cast<const bshort8*>(Aseg + (size_t)(r0 + r) * D_ + kk + q * 8);
            *reinterpret_cast<bshort8*>(&As[r][q * 8]) = av;
        }
        {
            const int col = tid >> 2, q = tid & 3;
            *reinterpret_cast<bshort8*>(&Bs[col][q * 8]) =
                *reinterpret_cast<const bshort8*>(W1t + (size_t)(c0 + col) * W1R + woff + kk + q * 8);
        }
        __syncthreads();
        bshort8 a[2], b[4];
#pragma unroll
        for (int mi = 0; mi < 2; ++mi)
            a[mi] = *reinterpret_cast<const bshort8*>(&As[wave * 32 + mi * 16 + row16][quad * 8]);
#pragma unroll
        for (int ni = 0; ni < 4; ++ni)
            b[ni] = *reinterpret_cast<const bshort8*>(&Bs[ni * 16 + row16][quad * 8]);
#pragma unroll
        for (int mi = 0; mi < 2; ++mi)
#pragma unroll
            for (int ni = 0; ni < 4; ++ni)
                acc[mi][ni] = __builtin_amdgcn_mfma_f32_16x16x32_bf16(a[mi], b[ni], acc[mi][ni], 0, 0, 0);
        __syncthreads();
    }
#pragma unroll
    for (int mi = 0; mi < 2; ++mi) {
#pragma unroll
        for (int ni = 0; ni < 4; ++ni) {
            const int rbase = r0 + wave * 32 + mi * 16 + quad * 4;
            const int col = c0 + ni * 16 + row16;
#pragma unroll
            for (int t = 0; t < 4; ++t)
                if (rbase + t < M) C[(size_t)(rbase + t) * H_ + col] = acc[mi][ni][t];
        }
    }
}

// ======== stage 6: gelu(Pe0+Pe1+Pe2+Pa+b1)@W2 + b2, scatter ========
__global__ __launch_bounds__(256) void score_k(const float* __restrict__ Pe3, const float* __restrict__ Pa3,
                                               const float* __restrict__ b1, const float* __restrict__ W2,
                                               const float* __restrict__ b2, const int* __restrict__ arg_map,
                                               float* __restrict__ out) {
    const int n = blockIdx.x >> 7, e = blockIdx.x & 127;
    const int tid = threadIdx.x;
    __shared__ float paS[A_ * H_];
    __shared__ float part[A_][4];
    float* orow = out + ((size_t)(n * E_ + e)) * RO_;
    if (tid < RO_) orow[tid] = -1000000.0f;
    for (int i = tid; i < A_ * H_; i += 256) {
        const size_t o = (size_t)n * A_ * H_ + i;
        paS[i] = Pa3[o] + Pa3[PASZ + o] + Pa3[2 * PASZ + o];
    }
    __syncthreads();
    const size_t ro = ((size_t)(n * E_ + e)) * H_;
    float acc[A_] = {};
    for (int h = tid; h < H_; h += 256) {
        const float pe = Pe3[ro + h] + Pe3[PESZ + ro + h] + Pe3[2 * PESZ + ro + h] + b1[h];
        const float w2 = W2[h];
#pragma unroll
        for (int a = 0; a < A_; ++a) {
            const float x = pe + paS[a * H_ + h];
            const float g = x * 0.5f * (1.0f + erf_fast(x * 0.70710678118654752f));
            acc[a] = fmaf(g, w2, acc[a]);
        }
    }
    const int lane = tid & 63, wv = tid >> 6;
#pragma unroll
    for (int a = 0; a < A_; ++a)
        for (int off = 32; off; off >>= 1) acc[a] += __shfl_down(acc[a], off, 64);
    if (lane == 0)
        for (int a = 0; a < A_; ++a) part[a][wv] = acc[a];
    __syncthreads();
    if (tid < A_) {
        const float s = part[tid][0] + part[tid][1] + part[tid][2] + part[tid][3] + b2[0];
        orow[arg_map[n * A_ + tid]] = s;
    }
}

extern "C" void kernel_launch(void* const* d_in, const int* in_sizes, int n_in,
                              void* d_out, int out_size, void* d_ws, size_t ws_size,
                              hipStream_t stream) {
    const float* all_emb = (const float*)d_in[0];
    const float* attn    = (const float*)d_in[1];
    const float* ent_map = (const float*)d_in[2];
    const float* argw    = (const float*)d_in[3];
    // d_in[4] is_triggers unused (reference dead code)
    const float* W1 = (const float*)d_in[5];
    const float* b1 = (const float*)d_in[6];
    const float* W2 = (const float*)d_in[7];
    const float* b2 = (const float*)d_in[8];
    const int* idxs    = (const int*)d_in[9];
    const int* arg_map = (const int*)d_in[10];
    float* out = (float*)d_out;

    float* ws = (float*)d_ws;
    // fp32 buffers (float offsets)
    float* entf = ws + 0;               // N*E*D           = 1,572,864
    float* Pe3  = ws + 1572864;         // 3*N*E*H         = 4,718,592  -> 6,291,456
    float* argE = ws + 6291456;         // N*A*D           =   110,592  -> 6,402,048
    float* wbuf = ws + 6402048;         // N*E*A           =    18,432  -> 6,420,480
    float* Pa3  = ws + 6420480;         // 3*N*A*H         =   331,776  -> 6,752,256
    // bf16 buffers (offsets in float-slots; sizes = shorts/2)
    short*          W1t     = (short*)(ws + 6752256);           // 768*4608 sh -> 8,521,728
    unsigned short* sentT   = (unsigned short*)(ws + 8521728);  // N*D*S sh    -> 9,308,160
    unsigned short* entmapT = (unsigned short*)(ws + 9308160);  // N*E*S sh    -> 9,439,232
    unsigned short* t2tT    = (unsigned short*)(ws + 9439232);  // N*S*S sh    -> 9,570,304
    unsigned short* M1bf    = (unsigned short*)(ws + 9570304);  // N*E*S sh    -> 9,701,376
    unsigned short* argEbf  = (unsigned short*)(ws + 9701376);  // N*A*D sh    -> 9,756,672
    unsigned short* u2ubf   = (unsigned short*)(ws + 9756672);  // N*A*D sh    -> 9,811,968 (pads argEbf overrun)
    unsigned short* entbf   = (unsigned short*)(ws + 9811968);  // N*E*D sh    -> 10,598,400
    unsigned short* Ah2hbf  = (unsigned short*)(ws + 10598400); // N*E*D sh    -> 11,384,832
    unsigned short* tokAbf  = (unsigned short*)(ws + 11384832); // N*E*D sh    -> 12,171,264
    unsigned short* argTbf  = (unsigned short*)(ws + 12171264); // N*A*D sh    -> 12,226,560
    // total ≈ 12.23M floats ≈ 48.9 MB

    // L1: all input-only transforms (2128 blocks, 16.9 KB LDS)
    stage1_k<<<GB_TOTAL, 256, 0, stream>>>(all_emb, idxs, ent_map, W1, argw, attn,
                                           sentT, entmapT, W1t, t2tT, argE, argEbf, u2ubf);

    // L2: ent = entmapT@sent (192) + M1 = entmapT@t2t (32)
    gemm_pair_k<<<224, 256, 0, stream>>>(entmapT, sentT, t2tT, entf, entbf, M1bf);

    // L3: Ah2h = M1@sent (192) + w via MFMA (16)
    gemm2_k<<<208, 256, 0, stream>>>(M1bf, sentT, entbf, argEbf, Ah2hbf, wbuf);

    // L4: tokA + argT (both consume wbuf)
    post_k<<<N_ * E_ + N_ * A_, 256, 0, stream>>>(wbuf, argE, entf, tokAbf, argTbf);

    // L5: MLP layer 1, K-split by segment into disjoint partials (648 blocks, no atomics)
    // W1 row blocks: [ent 0 | argE 768 | tokA 1536 | Ah2h 2304 | argT 3072 | u2u 3840]
    mfma_mlp_k<<<dim3(54, H_ / 64), 256, 0, stream>>>(entbf, tokAbf, Ah2hbf, argEbf, argTbf, u2ubf, W1t, Pe3, Pa3);

    // L6: gelu + W2 + scatter (sums the 3 partials on read)
    score_k<<<N_ * E_, 256, 0, stream>>>(Pe3, Pa3, b1, W2, b2, arg_map, out);

    (void)in_sizes; (void)n_in; (void)out_size; (void)ws_size;
}